// Round 13
// baseline (123.483 us; speedup 1.0000x reference)
//
#include <hip/hip_runtime.h>

typedef unsigned short u16;
typedef float f32x4 __attribute__((ext_vector_type(4)));
typedef short s16x8 __attribute__((ext_vector_type(8)));

#define GPTR(x) ((const __attribute__((address_space(1))) void*)(x))
#define LPTR(x) ((__attribute__((address_space(3))) void*)(x))

__device__ __forceinline__ u16 f32_to_bf16(float f) {
  unsigned u = __builtin_bit_cast(unsigned, f);
  u += 0x7FFFu + ((u >> 16) & 1u);
  return (u16)(u >> 16);
}
__device__ __forceinline__ float bf16_to_f32(u16 h) {
  unsigned u = ((unsigned)h) << 16;
  return __builtin_bit_cast(float, u);
}

// ---------- fused conversion: features -> Abf; [ml_text | mc_text padded] -> Bbf[3072][512] ----------
__global__ __launch_bounds__(256) void k_cvt_all(
    const float* __restrict__ A, const float* __restrict__ ML, const float* __restrict__ MC,
    u16* __restrict__ Abf, u16* __restrict__ Bbf)
{
  int i = blockIdx.x * 256 + threadIdx.x;   // 4-elem units; total 1441792
  const float* src; u16* dst; int idx;
  bool pad = false;
  if (i < 1048576) { src = A; dst = Abf; idx = i; }
  else {
    int j = i - 1048576;                     // 0..393215  (3072 rows x 128 units)
    if (j >= 393216) return;
    int row = j >> 7;
    dst = Bbf; idx = j;
    if (row < 2048) { src = ML; }
    else {
      int mcrow = row - 2048;
      src = MC; idx = j - 2048 * 128;
      pad = (mcrow >= 1000);
    }
  }
  ushort4 o = {0, 0, 0, 0};
  if (!pad) {
    float4 v = reinterpret_cast<const float4*>(src)[idx];
    o.x = f32_to_bf16(v.x); o.y = f32_to_bf16(v.y);
    o.z = f32_to_bf16(v.z); o.w = f32_to_bf16(v.w);
  }
  reinterpret_cast<ushort4*>(dst)[idx] = o;
}

// ---------- fused bf16 GEMM: 256x256 tile, 8-phase-style schedule (m201 template port) ----------
// 512 threads = 8 waves (2M x 4N; wave tile 128x64), BK=64, double-buffered LDS (128 KB),
// per K-tile 4 phases: {ds_read quadrant, stage, barrier, lgkmcnt(0), setprio, 16 MFMA, barrier}.
// Stage loads for kt+1 issued in phases 0-1 of kt -> boundary vmcnt(0) is effectively free.
// XOR-swizzled LDS (slot^(r&7)) via pre-swizzled global src + global_load_lds width=16.
// Col-blocks bn<8 (ml, cols 0..2047): store bf16 S + per-column sigmoid colsum partials.
// Col-blocks bn>=8 (mc, cols 2048..3071): per-row sum of exp(s) over local cols <1000.
__global__ __launch_bounds__(512, 2) void k_gemm_fused(
    const u16* __restrict__ A, const u16* __restrict__ B,
    u16* __restrict__ Sml, float* __restrict__ colpart, float* __restrict__ pexp,
    float scale)
{
  constexpr int K = 512;
  constexpr int BK = 64;
  __shared__ __align__(16) u16 As[2][256 * BK];   // 64 KB
  __shared__ __align__(16) u16 Bs[2][256 * BK];   // 64 KB
  __shared__ float sred[1024];                    // 4 KB (ml: cp[256]; mc: rex[256][4])

  const int tid  = threadIdx.x;
  const int lane = tid & 63;
  const int wave = tid >> 6;        // 0..7
  const int wr = wave >> 2;         // 0..1  (128-row halves)
  const int wc = wave & 3;          // 0..3  (64-col quarters)

  // bijective XCD swizzle: nwg=384 (384%8==0), q=48; consecutive wg share bm (A panel)
  int wg = (blockIdx.x & 7) * 48 + (blockIdx.x >> 3);
  const int bm = wg / 12;           // 0..31
  const int bn = wg % 12;           // 0..11
  const int row0 = bm * 256;
  const int col0 = bn * 256;
  const bool is_ml = (bn < 8);

  const int cr = (lane >> 4) * 4;   // C/D row base within 16-frag
  const int cc = lane & 15;         // C/D col within 16-frag

  f32x4 acc[8][4];
#pragma unroll
  for (int i = 0; i < 8; ++i)
#pragma unroll
    for (int j = 0; j < 4; ++j) acc[i][j] = (f32x4){0.f, 0.f, 0.f, 0.f};

  // staging descriptors: 2048 16B-slots per array; 512 threads -> 4 slot-quads each
  const u16* Agp[4]; const u16* Bgp[4]; int stb[4];
#pragma unroll
  for (int q = 0; q < 4; ++q) {
    int base = wave * 256 + q * 64;          // wave-uniform slot base
    int slot = base + lane;
    int r = slot >> 3, s = slot & 7;
    int sg = s ^ (r & 7);                    // pre-swizzled global source chunk
    stb[q] = base;
    Agp[q] = A + (size_t)(row0 + r) * K + sg * 8;
    Bgp[q] = B + (size_t)(col0 + r) * K + sg * 8;
  }
  auto stage_pair = [&](int buf, int k0, int q) {
    __builtin_amdgcn_global_load_lds(GPTR(Agp[q] + k0), LPTR(&As[buf][stb[q] * 8]), 16, 0, 0);
    __builtin_amdgcn_global_load_lds(GPTR(Bgp[q] + k0), LPTR(&Bs[buf][stb[q] * 8]), 16, 0, 0);
  };

  // prologue: stage K-tile 0 fully into buf0
#pragma unroll
  for (int q = 0; q < 4; ++q) stage_pair(0, 0, q);

#pragma unroll
  for (int kt = 0; kt < 8; ++kt) {
    const int cur = kt & 1;
    const int knext = (kt + 1) * BK;
    // K-tile boundary: kt's loads (issued 2-3 phases ago, except prologue) landed; all
    // waves past prior reads of buffer cur^1 -> staging may overwrite it.
    asm volatile("s_waitcnt vmcnt(0)" ::: "memory");
    __builtin_amdgcn_sched_barrier(0);
    __builtin_amdgcn_s_barrier();

    s16x8 bf[4][2];   // B-frags read in phase 0, reused across phases
#pragma unroll
    for (int p = 0; p < 4; ++p) {
      if (p == 0) {
#pragma unroll
        for (int nn = 0; nn < 4; ++nn)
#pragma unroll
          for (int ks = 0; ks < 2; ++ks) {
            int rc = wc * 64 + nn * 16 + (lane & 15);
            int ss = (ks * 4 + (lane >> 4)) ^ (rc & 7);
            bf[nn][ks] = *reinterpret_cast<const s16x8*>(&Bs[cur][rc * BK + ss * 8]);
          }
      }
      s16x8 af[2][2];
#pragma unroll
      for (int mm2 = 0; mm2 < 2; ++mm2)
#pragma unroll
        for (int ks = 0; ks < 2; ++ks) {
          int rr = wr * 128 + (p * 2 + mm2) * 16 + (lane & 15);
          int ss = (ks * 4 + (lane >> 4)) ^ (rr & 7);
          af[mm2][ks] = *reinterpret_cast<const s16x8*>(&As[cur][rr * BK + ss * 8]);
        }
      if (kt < 7 && p < 2) {           // 4 loads each in phases 0,1 -> 2-3 phases of cover
        stage_pair(cur ^ 1, knext, p * 2);
        stage_pair(cur ^ 1, knext, p * 2 + 1);
      }
      __builtin_amdgcn_s_barrier();
      asm volatile("s_waitcnt lgkmcnt(0)" ::: "memory");
      __builtin_amdgcn_sched_barrier(0);
      __builtin_amdgcn_s_setprio(1);
#pragma unroll
      for (int mm2 = 0; mm2 < 2; ++mm2)
#pragma unroll
        for (int nn = 0; nn < 4; ++nn)
#pragma unroll
          for (int ks = 0; ks < 2; ++ks)
            acc[p * 2 + mm2][nn] = __builtin_amdgcn_mfma_f32_16x16x32_bf16(
                af[mm2][ks], bf[nn][ks], acc[p * 2 + mm2][nn], 0, 0, 0);
      __builtin_amdgcn_s_setprio(0);
      __builtin_amdgcn_s_barrier();
    }
  }

  if (is_ml) {
    // store bf16 S  (C/D layout: col = lane&15, row = (lane>>4)*4 + reg)
#pragma unroll
    for (int mm = 0; mm < 8; ++mm) {
      int orow = row0 + wr * 128 + mm * 16 + cr;
#pragma unroll
      for (int nn = 0; nn < 4; ++nn) {
        int ocol = col0 + wc * 64 + nn * 16 + cc;
#pragma unroll
        for (int r = 0; r < 4; ++r)
          Sml[(size_t)(orow + r) * 2048 + ocol] = f32_to_bf16(acc[mm][nn][r] * scale);
      }
    }
    // per-column sigmoid colsum partials (2 atomic adds/slot from wr=0,1: commutative)
    if (tid < 256) sred[tid] = 0.f;
    __syncthreads();
#pragma unroll
    for (int nn = 0; nn < 4; ++nn) {
      float cs = 0.f;
#pragma unroll
      for (int mm = 0; mm < 8; ++mm)
#pragma unroll
        for (int r = 0; r < 4; ++r) {
          float s = acc[mm][nn][r] * scale;
          cs += 1.f / (1.f + __expf(-s));
        }
      cs += __shfl_xor(cs, 16);
      cs += __shfl_xor(cs, 32);
      if (lane < 16) atomicAdd(&sred[wc * 64 + nn * 16 + lane], cs);
    }
    __syncthreads();
    if (tid < 256) colpart[(size_t)bm * 2048 + col0 + tid] = sred[tid];
  } else {
    // per-row sum of exp(s) over valid mc cols (<1000 local)
    const int mccol0 = col0 - 2048;
#pragma unroll
    for (int mm = 0; mm < 8; ++mm) {
      float ex[4];
#pragma unroll
      for (int r = 0; r < 4; ++r) {
        float e = 0.f;
#pragma unroll
        for (int nn = 0; nn < 4; ++nn) {
          int ocol = mccol0 + wc * 64 + nn * 16 + cc;
          float s = acc[mm][nn][r] * scale;
          if (ocol < 1000) e += __expf(s);
        }
        ex[r] = e;
      }
#pragma unroll
      for (int o = 1; o < 16; o <<= 1)
#pragma unroll
        for (int r = 0; r < 4; ++r) ex[r] += __shfl_xor(ex[r], o);
      if ((lane & 15) == 0) {
#pragma unroll
        for (int r = 0; r < 4; ++r) {
          int lrow = wr * 128 + mm * 16 + cr + r;    // 0..255
          sred[lrow * 4 + wc] = ex[r];
        }
      }
    }
    __syncthreads();
    if (tid < 256) {
      size_t o = (size_t)(bn - 8) * 8192 + row0 + tid;
      pexp[o] = sred[tid * 4] + sred[tid * 4 + 1] + sred[tid * 4 + 2] + sred[tid * 4 + 3];
    }
  }
}

// ---------- merged small work: reduce_c | mc rowdot | R-fold ----------
__global__ __launch_bounds__(256) void k_misc(
    const float* __restrict__ part, const float* __restrict__ ratios, float* __restrict__ c,
    const float* __restrict__ T2, const u16* __restrict__ A, const u16* __restrict__ B,
    float* __restrict__ rowdot, const float* __restrict__ pexp, float* __restrict__ Rbuf,
    float scale)
{
  if (blockIdx.x < 8) {
    int j = blockIdx.x * 256 + threadIdx.x;  // 2048
    float s = 0.f;
    for (int ch = 0; ch < 32; ++ch) s += part[ch * 2048 + j];
    float b0 = ratios[j] * 8192.f;
    float b1 = (1.f - ratios[j]) * 8192.f;
    c[2 * j]     = b0 / s;
    c[2 * j + 1] = b1 / (8192.f - s);
    return;
  }
  if (blockIdx.x >= 2056) {
    int i = (blockIdx.x - 2056) * 256 + threadIdx.x;  // 8192 rows
    float e = 0.f;
#pragma unroll
    for (int ch = 0; ch < 4; ++ch) e += pexp[(size_t)ch * 8192 + i];
    Rbuf[i] = e;
    return;
  }
  // mc: per-row argmax of one-hot targets + bf16 dot (one-hot => trow=1)
  int wave = threadIdx.x >> 6, lane = threadIdx.x & 63;
  int row = (blockIdx.x - 8) * 4 + wave;
  const float4* t4 = reinterpret_cast<const float4*>(T2 + (size_t)row * 1000);
  int idx = -1;
#pragma unroll
  for (int g = 0; g < 4; ++g) {
    int j4 = lane + g * 64;
    if (j4 < 250) {
      float4 v = t4[j4];
      if (v.x > 0.5f) idx = j4 * 4;
      if (v.y > 0.5f) idx = j4 * 4 + 1;
      if (v.z > 0.5f) idx = j4 * 4 + 2;
      if (v.w > 0.5f) idx = j4 * 4 + 3;
    }
  }
#pragma unroll
  for (int o = 32; o; o >>= 1) idx = max(idx, __shfl_xor(idx, o));

  s16x8 va = *reinterpret_cast<const s16x8*>(A + (size_t)row * 512 + lane * 8);
  s16x8 vb = *reinterpret_cast<const s16x8*>(B + (size_t)(2048 + idx) * 512 + lane * 8);
  float d = 0.f;
#pragma unroll
  for (int k = 0; k < 8; ++k)
    d += bf16_to_f32((u16)va[k]) * bf16_to_f32((u16)vb[k]);
#pragma unroll
  for (int o = 32; o; o >>= 1) d += __shfl_xor(d, o);
  if (lane == 0) rowdot[row] = d * scale;
}

// ---------- ml pass 2: 1024 blocks x 256 threads; 8 rows x 8 cols per thread ----------
__global__ __launch_bounds__(256) void k_ml_pass2(
    const u16* __restrict__ S, const float* __restrict__ T, const float* __restrict__ c,
    float* __restrict__ part2, float* __restrict__ partT, float* __restrict__ partE)
{
  const int t = threadIdx.x;           // col group: cols t*8 .. t*8+7
  const int r0 = blockIdx.x * 8;       // 1024 blocks
  float c0[8], c1[8];
#pragma unroll
  for (int q = 0; q < 4; ++q) {
    float4 cv = reinterpret_cast<const float4*>(c)[t * 4 + q];
    c0[q * 2]     = cv.x; c1[q * 2]     = cv.y;
    c0[q * 2 + 1] = cv.z; c1[q * 2 + 1] = cv.w;
  }

  float q0s[8], ts[8];
#pragma unroll
  for (int k = 0; k < 8; ++k) { q0s[k] = 0.f; ts[k] = 0.f; }
  float tss = 0.f, ldsum = 0.f;

#pragma unroll 2
  for (int r = 0; r < 8; ++r) {
    size_t row = r0 + r;
    s16x8 sv = *reinterpret_cast<const s16x8*>(S + row * 2048 + t * 8);
    float4 ta = reinterpret_cast<const float4*>(T + row * 2048)[t * 2];
    float4 tb = reinterpret_cast<const float4*>(T + row * 2048)[t * 2 + 1];
    float tv[8] = {ta.x, ta.y, ta.z, ta.w, tb.x, tb.y, tb.z, tb.w};
#pragma unroll
    for (int k = 0; k < 8; ++k) {
      float s = bf16_to_f32((u16)sv[k]);
      float e = __expf(s);
      float n0 = e * c0[k];
      float den = n0 + c1[k];
      q0s[k] += n0 * __builtin_amdgcn_rcpf(den);
      ldsum  += __logf(den);
      ts[k]  += tv[k];
      tss    += tv[k] * s;
    }
  }
  float es = tss - ldsum;
#pragma unroll
  for (int k = 0; k < 8; ++k)
    es += __logf(c0[k] / c1[k]) * ts[k] + 8.f * __logf(c1[k]);

  float* p2 = part2 + (size_t)blockIdx.x * 2048 + t * 8;
  float* pT = partT + (size_t)blockIdx.x * 2048 + t * 8;
#pragma unroll
  for (int q = 0; q < 2; ++q) {
    reinterpret_cast<float4*>(p2)[q] = (float4){q0s[q*4], q0s[q*4+1], q0s[q*4+2], q0s[q*4+3]};
    reinterpret_cast<float4*>(pT)[q] = (float4){ts[q*4], ts[q*4+1], ts[q*4+2], ts[q*4+3]};
  }

  __shared__ float red[256];
  red[t] = es;
  __syncthreads();
  for (int o = 128; o; o >>= 1) {
    if (t < o) red[t] += red[t + o];
    __syncthreads();
  }
  if (t == 0) partE[blockIdx.x] = red[0];
}

// ---------- column reduce, stage A: 1024 chunks -> 64 ----------
__global__ __launch_bounds__(256) void k_colredA(
    const float* __restrict__ part2, const float* __restrict__ partT,
    float* __restrict__ pA2, float* __restrict__ pAT)
{
  int j = blockIdx.x * 256 + threadIdx.x;
  int ch0 = blockIdx.y * 16;               // 64 y-blocks, 16 chunks each
  float cs2 = 0.f, Tj = 0.f;
  for (int ch = ch0; ch < ch0 + 16; ++ch) {
    cs2 += part2[(size_t)ch * 2048 + j];
    Tj  += partT[(size_t)ch * 2048 + j];
  }
  pA2[(size_t)blockIdx.y * 2048 + j] = cs2;
  pAT[(size_t)blockIdx.y * 2048 + j] = Tj;
}

// ---------- column reduce, stage B: logs + per-column d-term ----------
__global__ __launch_bounds__(256) void k_colredB(
    const float* __restrict__ pA2, const float* __restrict__ pAT,
    const float* __restrict__ ratios, float* __restrict__ partCol)
{
  int j = blockIdx.x * 256 + threadIdx.x;
  float cs2 = 0.f, Tj = 0.f;
  for (int ch = 0; ch < 64; ++ch) {
    cs2 += pA2[(size_t)ch * 2048 + j];
    Tj  += pAT[(size_t)ch * 2048 + j];
  }
  float b0 = ratios[j] * 8192.f;
  float b1 = (1.f - ratios[j]) * 8192.f;
  float colp = Tj * __logf(b0 / cs2) + (8192.f - Tj) * __logf(b1 / (8192.f - cs2));
  __shared__ float red[256];
  red[threadIdx.x] = colp;
  __syncthreads();
  for (int o = 128; o; o >>= 1) {
    if (threadIdx.x < o) red[threadIdx.x] += red[threadIdx.x + o];
    __syncthreads();
  }
  if (threadIdx.x == 0) partCol[blockIdx.x] = red[0];
}

// ---------- finalize (lean) ----------
__global__ __launch_bounds__(1024) void k_finalize(
    const float* __restrict__ Rbuf, const float* __restrict__ rowdot,
    const int* __restrict__ ds, const float* __restrict__ partE,
    const float* __restrict__ partCol, float* __restrict__ out)
{
  __shared__ float red[1024];
  const int tid = threadIdx.x;

  auto bsum = [&](float v) -> float {
    __syncthreads();
    red[tid] = v;
    __syncthreads();
    for (int o = 512; o; o >>= 1) {
      if (tid < o) red[tid] += red[tid + o];
      __syncthreads();
    }
    return red[0];
  };

  float nmc = 0.f, nml = 0.f;
  for (int i = tid; i < 8192; i += 1024) {
    int d = ds[i];
    nmc += (d == 1) ? 1.f : 0.f;
    nml += (d == 0) ? 1.f : 0.f;
  }
  float n_mc = bsum(nmc);
  float n_ml = bsum(nml);
  float m = n_mc + 0.1f * n_ml;

  float a[8], Rv[8], rdv[8];
#pragma unroll
  for (int q = 0; q < 8; ++q) {
    int i = tid + q * 1024;
    Rv[q] = Rbuf[i]; rdv[q] = rowdot[i]; a[q] = 1.f;
  }
  for (int it = 0; it < 5; ++it) {
    float p = 0.f;
#pragma unroll
    for (int q = 0; q < 8; ++q) {
      a[q] = a[q] / fmaxf(Rv[q] * a[q], 1.f);
      p += Rv[q] * a[q];
    }
    float tot = bsum(p);
    float sc = m / tot;
#pragma unroll
    for (int q = 0; q < 8; ++q) a[q] *= sc;
  }
  float mcp = 0.f;
#pragma unroll
  for (int q = 0; q < 8; ++q)
    mcp += rdv[q] + __logf(a[q]);    // trow == 1 (one-hot targets)

  float ep = partE[tid];
  float cp = (tid < 8) ? partCol[tid] : 0.f;

  float total = bsum(-mcp - 0.5f * (cp + ep));
  if (tid == 0) out[0] = total;
}

extern "C" void kernel_launch(void* const* d_in, const int* in_sizes, int n_in,
                              void* d_out, int out_size, void* d_ws, size_t ws_size,
                              hipStream_t stream)
{
  const float* features = (const float*)d_in[0];  // [8192][512]
  const float* ml_text  = (const float*)d_in[1];  // [2048][512]
  const float* mc_text  = (const float*)d_in[2];  // [1000][512]
  const float* ml_tgt   = (const float*)d_in[3];  // [8192][2048]
  const float* mc_tgt   = (const float*)d_in[4];  // [8192][1000]
  const int*   dsidx    = (const int*)d_in[5];    // [8192]
  const float* ratios   = (const float*)d_in[6];  // [2048]
  float* out = (float*)d_out;

  char* ws = (char*)d_ws;
  size_t off = 0;
  auto alloc = [&](size_t bytes) -> void* {
    void* p = ws + off;
    off += (bytes + 255) & ~(size_t)255;
    return p;
  };
  u16*   Abf    = (u16*)alloc((size_t)8192 * 512 * 2);
  u16*   Bbf    = (u16*)alloc((size_t)3072 * 512 * 2);
  u16*   Sml    = (u16*)alloc((size_t)8192 * 2048 * 2);
  float* part1  = (float*)alloc((size_t)32 * 2048 * 4);
  float* cbuf   = (float*)alloc((size_t)2048 * 2 * 4);
  float* part2  = (float*)alloc((size_t)1024 * 2048 * 4);
  float* partT  = (float*)alloc((size_t)1024 * 2048 * 4);
  float* pA2    = (float*)alloc((size_t)64 * 2048 * 4);
  float* pAT    = (float*)alloc((size_t)64 * 2048 * 4);
  float* partE  = (float*)alloc((size_t)1024 * 4);
  float* partCol= (float*)alloc((size_t)8 * 4);
  float* pexp   = (float*)alloc((size_t)4 * 8192 * 4);
  float* Rbuf   = (float*)alloc((size_t)8192 * 4);
  float* rowdot = (float*)alloc((size_t)8192 * 4);

  k_cvt_all<<<(1441792 + 255) / 256, 256, 0, stream>>>(features, ml_text, mc_text, Abf, Bbf);

  const float scale = 1.0f / 0.07f;
  k_gemm_fused<<<384, 512, 0, stream>>>(Abf, Bbf, Sml, part1, pexp, scale);

  k_misc<<<2088, 256, 0, stream>>>(part1, ratios, cbuf, mc_tgt, Abf, Bbf, rowdot, pexp, Rbuf, scale);
  k_ml_pass2<<<1024, 256, 0, stream>>>(Sml, ml_tgt, cbuf, part2, partT, partE);
  k_colredA<<<dim3(8, 64), 256, 0, stream>>>(part2, partT, pA2, pAT);
  k_colredB<<<8, 256, 0, stream>>>(pA2, pAT, ratios, partCol);
  k_finalize<<<1, 1024, 0, stream>>>(Rbuf, rowdot, dsidx, partE, partCol, out);
}

// Round 14
// 111.972 us; speedup vs baseline: 1.1028x; 1.1028x over previous
//
#include <hip/hip_runtime.h>

typedef unsigned short u16;
typedef float f32x4 __attribute__((ext_vector_type(4)));
typedef short s16x8 __attribute__((ext_vector_type(8)));

#define GPTR(x) ((const __attribute__((address_space(1))) void*)(x))
#define LPTR(x) ((__attribute__((address_space(3))) void*)(x))

__device__ __forceinline__ u16 f32_to_bf16(float f) {
  unsigned u = __builtin_bit_cast(unsigned, f);
  u += 0x7FFFu + ((u >> 16) & 1u);
  return (u16)(u >> 16);
}
__device__ __forceinline__ float bf16_to_f32(u16 h) {
  unsigned u = ((unsigned)h) << 16;
  return __builtin_bit_cast(float, u);
}

// ---------- fused conversion: features -> Abf; [ml_text | mc_text padded] -> Bbf[3072][512] ----------
__global__ __launch_bounds__(256) void k_cvt_all(
    const float* __restrict__ A, const float* __restrict__ ML, const float* __restrict__ MC,
    u16* __restrict__ Abf, u16* __restrict__ Bbf)
{
  int i = blockIdx.x * 256 + threadIdx.x;   // 4-elem units; total 1441792
  const float* src; u16* dst; int idx;
  bool pad = false;
  if (i < 1048576) { src = A; dst = Abf; idx = i; }
  else {
    int j = i - 1048576;                     // 0..393215  (3072 rows x 128 units)
    if (j >= 393216) return;
    int row = j >> 7;
    dst = Bbf; idx = j;
    if (row < 2048) { src = ML; }
    else {
      int mcrow = row - 2048;
      src = MC; idx = j - 2048 * 128;
      pad = (mcrow >= 1000);
    }
  }
  ushort4 o = {0, 0, 0, 0};
  if (!pad) {
    float4 v = reinterpret_cast<const float4*>(src)[idx];
    o.x = f32_to_bf16(v.x); o.y = f32_to_bf16(v.y);
    o.z = f32_to_bf16(v.z); o.w = f32_to_bf16(v.w);
  }
  reinterpret_cast<ushort4*>(dst)[idx] = o;
}

// ---------- fused bf16 GEMM: 128x128 tile, 256 threads (4 waves 2x2; wave tile 64x64) ----------
// Double-buffered LDS (r6-proven schedule: stage(next) after barrier, drained at next barrier,
// overlapping MFMA of current tile). 64x64 wave tile = 0.5 ds_reads/MFMA (-33% LDS traffic
// vs 64x32). XOR-swizzled LDS via pre-swizzled global src + global_load_lds width=16.
// T5 setprio around MFMA cluster. 64.5 KB LDS -> 2 blocks/CU.
// Col-blocks bn<16 (ml): store bf16 S + per-column sigmoid colsum partials.
// Col-blocks bn>=16 (mc): per-row partial sums of exp(s) over cols<1000; no S store.
__global__ __launch_bounds__(256) void k_gemm_fused(
    const u16* __restrict__ A, const u16* __restrict__ B,
    u16* __restrict__ Sml, float* __restrict__ colpart, float* __restrict__ pexp,
    float scale)
{
  constexpr int K = 512;
  constexpr int BK = 64;
  __shared__ __align__(16) u16 As[2][128 * BK];   // 32 KB
  __shared__ __align__(16) u16 Bs[2][128 * BK];   // 32 KB
  __shared__ float sred[256];      // ml: cp[128]; mc: rex[128][2]

  const int tid  = threadIdx.x;
  const int lane = tid & 63;
  const int wave = tid >> 6;        // 0..3
  const int wr = wave >> 1;         // 0..1 (64-row halves)
  const int wc = wave & 1;          // 0..1 (64-col halves)

  // bijective XCD swizzle: nwg=1536, q=192; consecutive wg share bm (A panel)
  int wg = (blockIdx.x & 7) * 192 + (blockIdx.x >> 3);
  const int bm = wg / 24;           // 0..63
  const int bn = wg % 24;           // 0..23
  const int row0 = bm * 128;
  const int col0 = bn * 128;
  const bool is_ml = (bn < 16);

  const int cr = (lane >> 4) * 4;   // C/D row base within 16-frag
  const int cc = lane & 15;         // C/D col within 16-frag

  f32x4 acc[4][4];
#pragma unroll
  for (int i = 0; i < 4; ++i)
#pragma unroll
    for (int j = 0; j < 4; ++j) acc[i][j] = (f32x4){0.f, 0.f, 0.f, 0.f};

  // staging descriptors (loop-invariant): 1024 16B-slots per array; 256 threads -> 4 each
  const u16* Agp[4]; const u16* Bgp[4]; int stb[4];
#pragma unroll
  for (int q = 0; q < 4; ++q) {
    int base = wave * 256 + q * 64;          // wave-uniform slot base
    int slot = base + lane;
    int r = slot >> 3, s = slot & 7;
    int sg = s ^ (r & 7);                    // pre-swizzled global source chunk
    stb[q] = base;
    Agp[q] = A + (size_t)(row0 + r) * K + sg * 8;
    Bgp[q] = B + (size_t)(col0 + r) * K + sg * 8;
  }
  auto stage = [&](int buf, int k0) {
#pragma unroll
    for (int q = 0; q < 4; ++q) {
      __builtin_amdgcn_global_load_lds(GPTR(Agp[q] + k0), LPTR(&As[buf][stb[q] * 8]), 16, 0, 0);
      __builtin_amdgcn_global_load_lds(GPTR(Bgp[q] + k0), LPTR(&Bs[buf][stb[q] * 8]), 16, 0, 0);
    }
  };

  stage(0, 0);
#pragma unroll
  for (int t = 0; t < 8; ++t) {
    const int cur = t & 1;
    __syncthreads();                 // drains stage(cur) loads + prior ds_reads of cur^1
    if (t < 7) stage(cur ^ 1, (t + 1) * BK);
#pragma unroll
    for (int ks = 0; ks < 2; ++ks) {
      s16x8 af[4], bf[4];
#pragma unroll
      for (int mm = 0; mm < 4; ++mm) {
        int r = wr * 64 + mm * 16 + (lane & 15);
        int ss = (ks * 4 + (lane >> 4)) ^ (r & 7);
        af[mm] = *reinterpret_cast<const s16x8*>(&As[cur][r * BK + ss * 8]);
      }
#pragma unroll
      for (int nn = 0; nn < 4; ++nn) {
        int r = wc * 64 + nn * 16 + (lane & 15);
        int ss = (ks * 4 + (lane >> 4)) ^ (r & 7);
        bf[nn] = *reinterpret_cast<const s16x8*>(&Bs[cur][r * BK + ss * 8]);
      }
      __builtin_amdgcn_s_setprio(1);
#pragma unroll
      for (int mm = 0; mm < 4; ++mm)
#pragma unroll
        for (int nn = 0; nn < 4; ++nn)
          acc[mm][nn] = __builtin_amdgcn_mfma_f32_16x16x32_bf16(af[mm], bf[nn], acc[mm][nn], 0, 0, 0);
      __builtin_amdgcn_s_setprio(0);
    }
  }

  if (is_ml) {
    // store bf16 S  (C/D layout: col = lane&15, row = (lane>>4)*4 + reg)
#pragma unroll
    for (int mm = 0; mm < 4; ++mm) {
      int orow = row0 + wr * 64 + mm * 16 + cr;
#pragma unroll
      for (int nn = 0; nn < 4; ++nn) {
        int ocol = col0 + wc * 64 + nn * 16 + cc;
#pragma unroll
        for (int r = 0; r < 4; ++r)
          Sml[(size_t)(orow + r) * 2048 + ocol] = f32_to_bf16(acc[mm][nn][r] * scale);
      }
    }
    // per-column sigmoid colsum partials (2 atomic adds/slot from wr=0,1: commutative)
    if (tid < 128) sred[tid] = 0.f;
    __syncthreads();
#pragma unroll
    for (int nn = 0; nn < 4; ++nn) {
      float cs = 0.f;
#pragma unroll
      for (int mm = 0; mm < 4; ++mm)
#pragma unroll
        for (int r = 0; r < 4; ++r) {
          float s = acc[mm][nn][r] * scale;
          cs += 1.f / (1.f + __expf(-s));
        }
      cs += __shfl_xor(cs, 16);
      cs += __shfl_xor(cs, 32);
      if (lane < 16) atomicAdd(&sred[wc * 64 + nn * 16 + lane], cs);
    }
    __syncthreads();
    if (tid < 128) colpart[(size_t)bm * 2048 + col0 + tid] = sred[tid];
  } else {
    // per-row sum of exp(s) over valid mc cols (<1000)
    const int mccol0 = col0 - 2048;
    float ex[16];
#pragma unroll
    for (int mm = 0; mm < 4; ++mm)
#pragma unroll
      for (int r = 0; r < 4; ++r) {
        float e = 0.f;
#pragma unroll
        for (int nn = 0; nn < 4; ++nn) {
          int ocol = mccol0 + wc * 64 + nn * 16 + cc;
          float s = acc[mm][nn][r] * scale;
          if (ocol < 1000) e += __expf(s);
        }
        ex[mm * 4 + r] = e;
      }
#pragma unroll
    for (int o = 1; o < 16; o <<= 1)
#pragma unroll
      for (int q = 0; q < 16; ++q) ex[q] += __shfl_xor(ex[q], o);
    __syncthreads();
    if ((lane & 15) == 0) {
#pragma unroll
      for (int mm = 0; mm < 4; ++mm)
#pragma unroll
        for (int r = 0; r < 4; ++r) {
          int lrow = wr * 64 + mm * 16 + cr + r;      // 0..127
          sred[lrow * 2 + wc] = ex[mm * 4 + r];
        }
    }
    __syncthreads();
    if (tid < 128) {
      size_t o = (size_t)(bn - 16) * 8192 + row0 + tid;
      pexp[o] = sred[tid * 2] + sred[tid * 2 + 1];
    }
  }
}

// ---------- merged small work: reduce_c | mc rowdot | R-fold ----------
__global__ __launch_bounds__(256) void k_misc(
    const float* __restrict__ part, const float* __restrict__ ratios, float* __restrict__ c,
    const float* __restrict__ T2, const u16* __restrict__ A, const u16* __restrict__ B,
    float* __restrict__ rowdot, const float* __restrict__ pexp, float* __restrict__ Rbuf,
    float scale)
{
  if (blockIdx.x < 8) {
    int j = blockIdx.x * 256 + threadIdx.x;  // 2048
    float s = 0.f;
    for (int ch = 0; ch < 64; ++ch) s += part[ch * 2048 + j];
    float b0 = ratios[j] * 8192.f;
    float b1 = (1.f - ratios[j]) * 8192.f;
    c[2 * j]     = b0 / s;
    c[2 * j + 1] = b1 / (8192.f - s);
    return;
  }
  if (blockIdx.x >= 2056) {
    int i = (blockIdx.x - 2056) * 256 + threadIdx.x;  // 8192 rows
    float e = 0.f;
#pragma unroll
    for (int ch = 0; ch < 8; ++ch) e += pexp[(size_t)ch * 8192 + i];
    Rbuf[i] = e;
    return;
  }
  // mc: per-row argmax of one-hot targets + bf16 dot (one-hot => trow=1)
  int wave = threadIdx.x >> 6, lane = threadIdx.x & 63;
  int row = (blockIdx.x - 8) * 4 + wave;
  const float4* t4 = reinterpret_cast<const float4*>(T2 + (size_t)row * 1000);
  int idx = -1;
#pragma unroll
  for (int g = 0; g < 4; ++g) {
    int j4 = lane + g * 64;
    if (j4 < 250) {
      float4 v = t4[j4];
      if (v.x > 0.5f) idx = j4 * 4;
      if (v.y > 0.5f) idx = j4 * 4 + 1;
      if (v.z > 0.5f) idx = j4 * 4 + 2;
      if (v.w > 0.5f) idx = j4 * 4 + 3;
    }
  }
#pragma unroll
  for (int o = 32; o; o >>= 1) idx = max(idx, __shfl_xor(idx, o));

  s16x8 va = *reinterpret_cast<const s16x8*>(A + (size_t)row * 512 + lane * 8);
  s16x8 vb = *reinterpret_cast<const s16x8*>(B + (size_t)(2048 + idx) * 512 + lane * 8);
  float d = 0.f;
#pragma unroll
  for (int k = 0; k < 8; ++k)
    d += bf16_to_f32((u16)va[k]) * bf16_to_f32((u16)vb[k]);
#pragma unroll
  for (int o = 32; o; o >>= 1) d += __shfl_xor(d, o);
  if (lane == 0) rowdot[row] = d * scale;
}

// ---------- ml pass 2: 1024 blocks x 256 threads; 8 rows x 8 cols per thread ----------
__global__ __launch_bounds__(256) void k_ml_pass2(
    const u16* __restrict__ S, const float* __restrict__ T, const float* __restrict__ c,
    float* __restrict__ part2, float* __restrict__ partT, float* __restrict__ partE)
{
  const int t = threadIdx.x;           // col group: cols t*8 .. t*8+7
  const int r0 = blockIdx.x * 8;       // 1024 blocks
  float c0[8], c1[8];
#pragma unroll
  for (int q = 0; q < 4; ++q) {
    float4 cv = reinterpret_cast<const float4*>(c)[t * 4 + q];
    c0[q * 2]     = cv.x; c1[q * 2]     = cv.y;
    c0[q * 2 + 1] = cv.z; c1[q * 2 + 1] = cv.w;
  }

  float q0s[8], ts[8];
#pragma unroll
  for (int k = 0; k < 8; ++k) { q0s[k] = 0.f; ts[k] = 0.f; }
  float tss = 0.f, ldsum = 0.f;

#pragma unroll 2
  for (int r = 0; r < 8; ++r) {
    size_t row = r0 + r;
    s16x8 sv = *reinterpret_cast<const s16x8*>(S + row * 2048 + t * 8);
    float4 ta = reinterpret_cast<const float4*>(T + row * 2048)[t * 2];
    float4 tb = reinterpret_cast<const float4*>(T + row * 2048)[t * 2 + 1];
    float tv[8] = {ta.x, ta.y, ta.z, ta.w, tb.x, tb.y, tb.z, tb.w};
#pragma unroll
    for (int k = 0; k < 8; ++k) {
      float s = bf16_to_f32((u16)sv[k]);
      float e = __expf(s);
      float n0 = e * c0[k];
      float den = n0 + c1[k];
      q0s[k] += n0 * __builtin_amdgcn_rcpf(den);
      ldsum  += __logf(den);
      ts[k]  += tv[k];
      tss    += tv[k] * s;
    }
  }
  float es = tss - ldsum;
#pragma unroll
  for (int k = 0; k < 8; ++k)
    es += __logf(c0[k] / c1[k]) * ts[k] + 8.f * __logf(c1[k]);

  float* p2 = part2 + (size_t)blockIdx.x * 2048 + t * 8;
  float* pT = partT + (size_t)blockIdx.x * 2048 + t * 8;
#pragma unroll
  for (int q = 0; q < 2; ++q) {
    reinterpret_cast<float4*>(p2)[q] = (float4){q0s[q*4], q0s[q*4+1], q0s[q*4+2], q0s[q*4+3]};
    reinterpret_cast<float4*>(pT)[q] = (float4){ts[q*4], ts[q*4+1], ts[q*4+2], ts[q*4+3]};
  }

  __shared__ float red[256];
  red[t] = es;
  __syncthreads();
  for (int o = 128; o; o >>= 1) {
    if (t < o) red[t] += red[t + o];
    __syncthreads();
  }
  if (t == 0) partE[blockIdx.x] = red[0];
}

// ---------- column reduce, stage A: 1024 chunks -> 64 ----------
__global__ __launch_bounds__(256) void k_colredA(
    const float* __restrict__ part2, const float* __restrict__ partT,
    float* __restrict__ pA2, float* __restrict__ pAT)
{
  int j = blockIdx.x * 256 + threadIdx.x;
  int ch0 = blockIdx.y * 16;               // 64 y-blocks, 16 chunks each
  float cs2 = 0.f, Tj = 0.f;
  for (int ch = ch0; ch < ch0 + 16; ++ch) {
    cs2 += part2[(size_t)ch * 2048 + j];
    Tj  += partT[(size_t)ch * 2048 + j];
  }
  pA2[(size_t)blockIdx.y * 2048 + j] = cs2;
  pAT[(size_t)blockIdx.y * 2048 + j] = Tj;
}

// ---------- column reduce, stage B: logs + per-column d-term ----------
__global__ __launch_bounds__(256) void k_colredB(
    const float* __restrict__ pA2, const float* __restrict__ pAT,
    const float* __restrict__ ratios, float* __restrict__ partCol)
{
  int j = blockIdx.x * 256 + threadIdx.x;
  float cs2 = 0.f, Tj = 0.f;
  for (int ch = 0; ch < 64; ++ch) {
    cs2 += pA2[(size_t)ch * 2048 + j];
    Tj  += pAT[(size_t)ch * 2048 + j];
  }
  float b0 = ratios[j] * 8192.f;
  float b1 = (1.f - ratios[j]) * 8192.f;
  float colp = Tj * __logf(b0 / cs2) + (8192.f - Tj) * __logf(b1 / (8192.f - cs2));
  __shared__ float red[256];
  red[threadIdx.x] = colp;
  __syncthreads();
  for (int o = 128; o; o >>= 1) {
    if (threadIdx.x < o) red[threadIdx.x] += red[threadIdx.x + o];
    __syncthreads();
  }
  if (threadIdx.x == 0) partCol[blockIdx.x] = red[0];
}

// ---------- finalize (lean) ----------
__global__ __launch_bounds__(1024) void k_finalize(
    const float* __restrict__ Rbuf, const float* __restrict__ rowdot,
    const int* __restrict__ ds, const float* __restrict__ partE,
    const float* __restrict__ partCol, float* __restrict__ out)
{
  __shared__ float red[1024];
  const int tid = threadIdx.x;

  auto bsum = [&](float v) -> float {
    __syncthreads();
    red[tid] = v;
    __syncthreads();
    for (int o = 512; o; o >>= 1) {
      if (tid < o) red[tid] += red[tid + o];
      __syncthreads();
    }
    return red[0];
  };

  float nmc = 0.f, nml = 0.f;
  for (int i = tid; i < 8192; i += 1024) {
    int d = ds[i];
    nmc += (d == 1) ? 1.f : 0.f;
    nml += (d == 0) ? 1.f : 0.f;
  }
  float n_mc = bsum(nmc);
  float n_ml = bsum(nml);
  float m = n_mc + 0.1f * n_ml;

  float a[8], Rv[8], rdv[8];
#pragma unroll
  for (int q = 0; q < 8; ++q) {
    int i = tid + q * 1024;
    Rv[q] = Rbuf[i]; rdv[q] = rowdot[i]; a[q] = 1.f;
  }
  for (int it = 0; it < 5; ++it) {
    float p = 0.f;
#pragma unroll
    for (int q = 0; q < 8; ++q) {
      a[q] = a[q] / fmaxf(Rv[q] * a[q], 1.f);
      p += Rv[q] * a[q];
    }
    float tot = bsum(p);
    float sc = m / tot;
#pragma unroll
    for (int q = 0; q < 8; ++q) a[q] *= sc;
  }
  float mcp = 0.f;
#pragma unroll
  for (int q = 0; q < 8; ++q)
    mcp += rdv[q] + __logf(a[q]);    // trow == 1 (one-hot targets)

  float ep = partE[tid];
  float cp = (tid < 8) ? partCol[tid] : 0.f;

  float total = bsum(-mcp - 0.5f * (cp + ep));
  if (tid == 0) out[0] = total;
}

extern "C" void kernel_launch(void* const* d_in, const int* in_sizes, int n_in,
                              void* d_out, int out_size, void* d_ws, size_t ws_size,
                              hipStream_t stream)
{
  const float* features = (const float*)d_in[0];  // [8192][512]
  const float* ml_text  = (const float*)d_in[1];  // [2048][512]
  const float* mc_text  = (const float*)d_in[2];  // [1000][512]
  const float* ml_tgt   = (const float*)d_in[3];  // [8192][2048]
  const float* mc_tgt   = (const float*)d_in[4];  // [8192][1000]
  const int*   dsidx    = (const int*)d_in[5];    // [8192]
  const float* ratios   = (const float*)d_in[6];  // [2048]
  float* out = (float*)d_out;

  char* ws = (char*)d_ws;
  size_t off = 0;
  auto alloc = [&](size_t bytes) -> void* {
    void* p = ws + off;
    off += (bytes + 255) & ~(size_t)255;
    return p;
  };
  u16*   Abf    = (u16*)alloc((size_t)8192 * 512 * 2);
  u16*   Bbf    = (u16*)alloc((size_t)3072 * 512 * 2);
  u16*   Sml    = (u16*)alloc((size_t)8192 * 2048 * 2);
  float* part1  = (float*)alloc((size_t)64 * 2048 * 4);
  float* cbuf   = (float*)alloc((size_t)2048 * 2 * 4);
  float* part2  = (float*)alloc((size_t)1024 * 2048 * 4);
  float* partT  = (float*)alloc((size_t)1024 * 2048 * 4);
  float* pA2    = (float*)alloc((size_t)64 * 2048 * 4);
  float* pAT    = (float*)alloc((size_t)64 * 2048 * 4);
  float* partE  = (float*)alloc((size_t)1024 * 4);
  float* partCol= (float*)alloc((size_t)8 * 4);
  float* pexp   = (float*)alloc((size_t)8 * 8192 * 4);
  float* Rbuf   = (float*)alloc((size_t)8192 * 4);
  float* rowdot = (float*)alloc((size_t)8192 * 4);

  k_cvt_all<<<(1441792 + 255) / 256, 256, 0, stream>>>(features, ml_text, mc_text, Abf, Bbf);

  const float scale = 1.0f / 0.07f;
  k_gemm_fused<<<1536, 256, 0, stream>>>(Abf, Bbf, Sml, part1, pexp, scale);

  k_misc<<<2088, 256, 0, stream>>>(part1, ratios, cbuf, mc_tgt, Abf, Bbf, rowdot, pexp, Rbuf, scale);
  k_ml_pass2<<<1024, 256, 0, stream>>>(Sml, ml_tgt, cbuf, part2, partT, partE);
  k_colredA<<<dim3(8, 64), 256, 0, stream>>>(part2, partT, pA2, pAT);
  k_colredB<<<8, 256, 0, stream>>>(pA2, pAT, ratios, partCol);
  k_finalize<<<1, 1024, 0, stream>>>(Rbuf, rowdot, dsidx, partE, partCol, out);
}

// Round 15
// 110.364 us; speedup vs baseline: 1.1189x; 1.0146x over previous
//
#include <hip/hip_runtime.h>

typedef unsigned short u16;
typedef float f32x4 __attribute__((ext_vector_type(4)));
typedef short s16x8 __attribute__((ext_vector_type(8)));

#define GPTR(x) ((const __attribute__((address_space(1))) void*)(x))
#define LPTR(x) ((__attribute__((address_space(3))) void*)(x))

__device__ __forceinline__ u16 f32_to_bf16(float f) {
  unsigned u = __builtin_bit_cast(unsigned, f);
  u += 0x7FFFu + ((u >> 16) & 1u);
  return (u16)(u >> 16);
}
__device__ __forceinline__ float bf16_to_f32(u16 h) {
  unsigned u = ((unsigned)h) << 16;
  return __builtin_bit_cast(float, u);
}

// ---------- fused conversion: features -> Abf; [ml_text | mc_text padded] -> Bbf[3072][512] ----------
__global__ __launch_bounds__(256) void k_cvt_all(
    const float* __restrict__ A, const float* __restrict__ ML, const float* __restrict__ MC,
    u16* __restrict__ Abf, u16* __restrict__ Bbf)
{
  int i = blockIdx.x * 256 + threadIdx.x;   // 4-elem units; total 1441792
  const float* src; u16* dst; int idx;
  bool pad = false;
  if (i < 1048576) { src = A; dst = Abf; idx = i; }
  else {
    int j = i - 1048576;                     // 0..393215  (3072 rows x 128 units)
    if (j >= 393216) return;
    int row = j >> 7;
    dst = Bbf; idx = j;
    if (row < 2048) { src = ML; }
    else {
      int mcrow = row - 2048;
      src = MC; idx = j - 2048 * 128;
      pad = (mcrow >= 1000);
    }
  }
  ushort4 o = {0, 0, 0, 0};
  if (!pad) {
    float4 v = reinterpret_cast<const float4*>(src)[idx];
    o.x = f32_to_bf16(v.x); o.y = f32_to_bf16(v.y);
    o.z = f32_to_bf16(v.z); o.w = f32_to_bf16(v.w);
  }
  reinterpret_cast<ushort4*>(dst)[idx] = o;
}

// ---------- fused bf16 GEMM (r6 config + T5 setprio): S = scale * A[8192][512] * B[3072][512]^T ----------
// 128x128 tile, 512 threads (8 waves, 2x4; wave tile 64x32), BK=64, double-buffered LDS,
// prefetch issued after barrier (drained at NEXT barrier -> overlaps MFMA of current tile).
// XOR-swizzled LDS via pre-swizzled global src + global_load_lds width=16.
// Col-blocks bn<16 (ml): store bf16 S + per-column sigmoid colsum partials.
// Col-blocks bn>=16 (mc): per-row partial sums of exp(s) over cols<1000; no S store.
__global__ __launch_bounds__(512) void k_gemm_fused(
    const u16* __restrict__ A, const u16* __restrict__ B,
    u16* __restrict__ Sml, float* __restrict__ colpart, float* __restrict__ pexp,
    float scale)
{
  constexpr int K = 512;
  constexpr int BK = 64;
  __shared__ __align__(16) u16 As[2][128 * BK];
  __shared__ __align__(16) u16 Bs[2][128 * BK];
  __shared__ float sred[128 * 4];   // ml: cp[128]; mc: rex[128][4]

  const int tid  = threadIdx.x;
  const int lane = tid & 63;
  const int wave = tid >> 6;        // 0..7
  const int wr = wave >> 2;         // 0..1  (64-row halves)
  const int wc = wave & 3;          // 0..3  (32-col quarters)

  // bijective XCD swizzle: nwg=1536, q=192; then bm = wg/24 (24 consecutive share A-panel)
  int wg = (blockIdx.x & 7) * 192 + (blockIdx.x >> 3);
  const int bm = wg / 24;
  const int bn = wg % 24;
  const int row0 = bm * 128;
  const int col0 = bn * 128;
  const bool is_ml = (bn < 16);

  const int cr = (lane >> 4) * 4;   // C/D row base within 16-frag
  const int cc = lane & 15;         // C/D col within 16-frag

  if (tid < 128) sred[tid] = 0.f;   // cp init (ml)

  f32x4 acc[4][2];
#pragma unroll
  for (int i = 0; i < 4; ++i)
#pragma unroll
    for (int j = 0; j < 2; ++j) acc[i][j] = (f32x4){0.f, 0.f, 0.f, 0.f};

  // staging: 1024 16B-slots per array; 512 threads -> 2 slots each per array
  auto stage = [&](int buf, int k0) {
#pragma unroll
    for (int q = 0; q < 2; ++q) {
      int base = wave * 128 + q * 64;        // wave-uniform slot base
      int slot = base + lane;
      int r = slot >> 3, s = slot & 7;
      int sg = s ^ (r & 7);                  // pre-swizzled global source chunk
      __builtin_amdgcn_global_load_lds(GPTR(A + (size_t)(row0 + r) * K + k0 + sg * 8),
                                       LPTR(&As[buf][base * 8]), 16, 0, 0);
      __builtin_amdgcn_global_load_lds(GPTR(B + (size_t)(col0 + r) * K + k0 + sg * 8),
                                       LPTR(&Bs[buf][base * 8]), 16, 0, 0);
    }
  };

  stage(0, 0);
  for (int t = 0; t < 8; ++t) {
    const int cur = t & 1;
    __syncthreads();                 // drains stage(cur) loads + prior ds_reads
    if (t < 7) stage(cur ^ 1, (t + 1) * BK);
#pragma unroll
    for (int ks = 0; ks < 2; ++ks) {
      s16x8 af[4], bf[2];
#pragma unroll
      for (int mm = 0; mm < 4; ++mm) {
        int r = wr * 64 + mm * 16 + (lane & 15);
        int ss = (ks * 4 + (lane >> 4)) ^ (r & 7);
        af[mm] = *reinterpret_cast<const s16x8*>(&As[cur][r * BK + ss * 8]);
      }
#pragma unroll
      for (int nn = 0; nn < 2; ++nn) {
        int r = wc * 32 + nn * 16 + (lane & 15);
        int ss = (ks * 4 + (lane >> 4)) ^ (r & 7);
        bf[nn] = *reinterpret_cast<const s16x8*>(&Bs[cur][r * BK + ss * 8]);
      }
      __builtin_amdgcn_s_setprio(1);
#pragma unroll
      for (int mm = 0; mm < 4; ++mm)
#pragma unroll
        for (int nn = 0; nn < 2; ++nn)
          acc[mm][nn] = __builtin_amdgcn_mfma_f32_16x16x32_bf16(af[mm], bf[nn], acc[mm][nn], 0, 0, 0);
      __builtin_amdgcn_s_setprio(0);
    }
  }

  if (is_ml) {
    // store bf16 S  (C/D layout: col = lane&15, row = (lane>>4)*4 + reg)
#pragma unroll
    for (int mm = 0; mm < 4; ++mm) {
      int orow = row0 + wr * 64 + mm * 16 + cr;
#pragma unroll
      for (int nn = 0; nn < 2; ++nn) {
        int ocol = col0 + wc * 32 + nn * 16 + cc;
#pragma unroll
        for (int r = 0; r < 4; ++r)
          Sml[(size_t)(orow + r) * 2048 + ocol] = f32_to_bf16(acc[mm][nn][r] * scale);
      }
    }
    // per-column sigmoid colsum partials
    __syncthreads();   // sred init visible
#pragma unroll
    for (int nn = 0; nn < 2; ++nn) {
      float cs = 0.f;
#pragma unroll
      for (int mm = 0; mm < 4; ++mm)
#pragma unroll
        for (int r = 0; r < 4; ++r) {
          float s = acc[mm][nn][r] * scale;
          cs += 1.f / (1.f + __expf(-s));
        }
      cs += __shfl_xor(cs, 16);
      cs += __shfl_xor(cs, 32);
      if (lane < 16) atomicAdd(&sred[wc * 32 + nn * 16 + lane], cs);  // 2 adds/slot (wr=0,1)
    }
    __syncthreads();
    if (tid < 128) colpart[(size_t)bm * 2048 + col0 + tid] = sred[tid];
  } else {
    // per-row sum of exp(s) over valid cols (<1000 local)
    const int mccol0 = col0 - 2048;
    float ex[16];
#pragma unroll
    for (int mm = 0; mm < 4; ++mm)
#pragma unroll
      for (int r = 0; r < 4; ++r) {
        float e = 0.f;
#pragma unroll
        for (int nn = 0; nn < 2; ++nn) {
          int ocol = mccol0 + wc * 32 + nn * 16 + cc;
          float s = acc[mm][nn][r] * scale;
          if (ocol < 1000) e += __expf(s);
        }
        ex[mm * 4 + r] = e;
      }
#pragma unroll
    for (int o = 1; o < 16; o <<= 1)
#pragma unroll
      for (int q = 0; q < 16; ++q) ex[q] += __shfl_xor(ex[q], o);
    __syncthreads();
    if ((lane & 15) == 0) {
#pragma unroll
      for (int mm = 0; mm < 4; ++mm)
#pragma unroll
        for (int r = 0; r < 4; ++r) {
          int lrow = wr * 64 + mm * 16 + cr + r;
          sred[lrow * 4 + wc] = ex[mm * 4 + r];
        }
    }
    __syncthreads();
    if (tid < 128) {
      size_t o = (size_t)(bn - 16) * 8192 + row0 + tid;
      pexp[o] = sred[tid * 4] + sred[tid * 4 + 1] + sred[tid * 4 + 2] + sred[tid * 4 + 3];
    }
  }
}

// ---------- merged small work: reduce_c | mc rowdot | R-fold ----------
__global__ __launch_bounds__(256) void k_misc(
    const float* __restrict__ part, const float* __restrict__ ratios, float* __restrict__ c,
    const float* __restrict__ T2, const u16* __restrict__ A, const u16* __restrict__ B,
    float* __restrict__ rowdot, const float* __restrict__ pexp, float* __restrict__ Rbuf,
    float scale)
{
  if (blockIdx.x < 8) {
    int j = blockIdx.x * 256 + threadIdx.x;  // 2048
    float s = 0.f;
    for (int ch = 0; ch < 64; ++ch) s += part[ch * 2048 + j];
    float b0 = ratios[j] * 8192.f;
    float b1 = (1.f - ratios[j]) * 8192.f;
    c[2 * j]     = b0 / s;
    c[2 * j + 1] = b1 / (8192.f - s);
    return;
  }
  if (blockIdx.x >= 2056) {
    int i = (blockIdx.x - 2056) * 256 + threadIdx.x;  // 8192 rows
    float e = 0.f;
#pragma unroll
    for (int ch = 0; ch < 8; ++ch) e += pexp[(size_t)ch * 8192 + i];
    Rbuf[i] = e;
    return;
  }
  // mc: per-row argmax of one-hot targets + bf16 dot (one-hot => trow=1)
  int wave = threadIdx.x >> 6, lane = threadIdx.x & 63;
  int row = (blockIdx.x - 8) * 4 + wave;
  const float4* t4 = reinterpret_cast<const float4*>(T2 + (size_t)row * 1000);
  int idx = -1;
#pragma unroll
  for (int g = 0; g < 4; ++g) {
    int j4 = lane + g * 64;
    if (j4 < 250) {
      float4 v = t4[j4];
      if (v.x > 0.5f) idx = j4 * 4;
      if (v.y > 0.5f) idx = j4 * 4 + 1;
      if (v.z > 0.5f) idx = j4 * 4 + 2;
      if (v.w > 0.5f) idx = j4 * 4 + 3;
    }
  }
#pragma unroll
  for (int o = 32; o; o >>= 1) idx = max(idx, __shfl_xor(idx, o));

  s16x8 va = *reinterpret_cast<const s16x8*>(A + (size_t)row * 512 + lane * 8);
  s16x8 vb = *reinterpret_cast<const s16x8*>(B + (size_t)(2048 + idx) * 512 + lane * 8);
  float d = 0.f;
#pragma unroll
  for (int k = 0; k < 8; ++k)
    d += bf16_to_f32((u16)va[k]) * bf16_to_f32((u16)vb[k]);
#pragma unroll
  for (int o = 32; o; o >>= 1) d += __shfl_xor(d, o);
  if (lane == 0) rowdot[row] = d * scale;
}

// ---------- ml pass 2: 1024 blocks x 256 threads; 8 rows x 8 cols per thread ----------
__global__ __launch_bounds__(256) void k_ml_pass2(
    const u16* __restrict__ S, const float* __restrict__ T, const float* __restrict__ c,
    float* __restrict__ part2, float* __restrict__ partT, float* __restrict__ partE)
{
  const int t = threadIdx.x;           // col group: cols t*8 .. t*8+7
  const int r0 = blockIdx.x * 8;       // 1024 blocks
  float c0[8], c1[8];
#pragma unroll
  for (int q = 0; q < 4; ++q) {
    float4 cv = reinterpret_cast<const float4*>(c)[t * 4 + q];
    c0[q * 2]     = cv.x; c1[q * 2]     = cv.y;
    c0[q * 2 + 1] = cv.z; c1[q * 2 + 1] = cv.w;
  }

  float q0s[8], ts[8];
#pragma unroll
  for (int k = 0; k < 8; ++k) { q0s[k] = 0.f; ts[k] = 0.f; }
  float tss = 0.f, ldsum = 0.f;

#pragma unroll 2
  for (int r = 0; r < 8; ++r) {
    size_t row = r0 + r;
    s16x8 sv = *reinterpret_cast<const s16x8*>(S + row * 2048 + t * 8);
    float4 ta = reinterpret_cast<const float4*>(T + row * 2048)[t * 2];
    float4 tb = reinterpret_cast<const float4*>(T + row * 2048)[t * 2 + 1];
    float tv[8] = {ta.x, ta.y, ta.z, ta.w, tb.x, tb.y, tb.z, tb.w};
#pragma unroll
    for (int k = 0; k < 8; ++k) {
      float s = bf16_to_f32((u16)sv[k]);
      float e = __expf(s);
      float n0 = e * c0[k];
      float den = n0 + c1[k];
      q0s[k] += n0 * __builtin_amdgcn_rcpf(den);
      ldsum  += __logf(den);
      ts[k]  += tv[k];
      tss    += tv[k] * s;
    }
  }
  float es = tss - ldsum;
#pragma unroll
  for (int k = 0; k < 8; ++k)
    es += __logf(c0[k] / c1[k]) * ts[k] + 8.f * __logf(c1[k]);

  float* p2 = part2 + (size_t)blockIdx.x * 2048 + t * 8;
  float* pT = partT + (size_t)blockIdx.x * 2048 + t * 8;
#pragma unroll
  for (int q = 0; q < 2; ++q) {
    reinterpret_cast<float4*>(p2)[q] = (float4){q0s[q*4], q0s[q*4+1], q0s[q*4+2], q0s[q*4+3]};
    reinterpret_cast<float4*>(pT)[q] = (float4){ts[q*4], ts[q*4+1], ts[q*4+2], ts[q*4+3]};
  }

  __shared__ float red[256];
  red[t] = es;
  __syncthreads();
  for (int o = 128; o; o >>= 1) {
    if (t < o) red[t] += red[t + o];
    __syncthreads();
  }
  if (t == 0) partE[blockIdx.x] = red[0];
}

// ---------- column reduce, stage A: 1024 chunks -> 64 ----------
__global__ __launch_bounds__(256) void k_colredA(
    const float* __restrict__ part2, const float* __restrict__ partT,
    float* __restrict__ pA2, float* __restrict__ pAT)
{
  int j = blockIdx.x * 256 + threadIdx.x;
  int ch0 = blockIdx.y * 16;               // 64 y-blocks, 16 chunks each
  float cs2 = 0.f, Tj = 0.f;
  for (int ch = ch0; ch < ch0 + 16; ++ch) {
    cs2 += part2[(size_t)ch * 2048 + j];
    Tj  += partT[(size_t)ch * 2048 + j];
  }
  pA2[(size_t)blockIdx.y * 2048 + j] = cs2;
  pAT[(size_t)blockIdx.y * 2048 + j] = Tj;
}

// ---------- column reduce, stage B: logs + per-column d-term ----------
__global__ __launch_bounds__(256) void k_colredB(
    const float* __restrict__ pA2, const float* __restrict__ pAT,
    const float* __restrict__ ratios, float* __restrict__ partCol)
{
  int j = blockIdx.x * 256 + threadIdx.x;
  float cs2 = 0.f, Tj = 0.f;
  for (int ch = 0; ch < 64; ++ch) {
    cs2 += pA2[(size_t)ch * 2048 + j];
    Tj  += pAT[(size_t)ch * 2048 + j];
  }
  float b0 = ratios[j] * 8192.f;
  float b1 = (1.f - ratios[j]) * 8192.f;
  float colp = Tj * __logf(b0 / cs2) + (8192.f - Tj) * __logf(b1 / (8192.f - cs2));
  __shared__ float red[256];
  red[threadIdx.x] = colp;
  __syncthreads();
  for (int o = 128; o; o >>= 1) {
    if (threadIdx.x < o) red[threadIdx.x] += red[threadIdx.x + o];
    __syncthreads();
  }
  if (threadIdx.x == 0) partCol[blockIdx.x] = red[0];
}

// ---------- finalize (lean) ----------
__global__ __launch_bounds__(1024) void k_finalize(
    const float* __restrict__ Rbuf, const float* __restrict__ rowdot,
    const int* __restrict__ ds, const float* __restrict__ partE,
    const float* __restrict__ partCol, float* __restrict__ out)
{
  __shared__ float red[1024];
  const int tid = threadIdx.x;

  auto bsum = [&](float v) -> float {
    __syncthreads();
    red[tid] = v;
    __syncthreads();
    for (int o = 512; o; o >>= 1) {
      if (tid < o) red[tid] += red[tid + o];
      __syncthreads();
    }
    return red[0];
  };

  float nmc = 0.f, nml = 0.f;
  for (int i = tid; i < 8192; i += 1024) {
    int d = ds[i];
    nmc += (d == 1) ? 1.f : 0.f;
    nml += (d == 0) ? 1.f : 0.f;
  }
  float n_mc = bsum(nmc);
  float n_ml = bsum(nml);
  float m = n_mc + 0.1f * n_ml;

  float a[8], Rv[8], rdv[8];
#pragma unroll
  for (int q = 0; q < 8; ++q) {
    int i = tid + q * 1024;
    Rv[q] = Rbuf[i]; rdv[q] = rowdot[i]; a[q] = 1.f;
  }
  for (int it = 0; it < 5; ++it) {
    float p = 0.f;
#pragma unroll
    for (int q = 0; q < 8; ++q) {
      a[q] = a[q] / fmaxf(Rv[q] * a[q], 1.f);
      p += Rv[q] * a[q];
    }
    float tot = bsum(p);
    float sc = m / tot;
#pragma unroll
    for (int q = 0; q < 8; ++q) a[q] *= sc;
  }
  float mcp = 0.f;
#pragma unroll
  for (int q = 0; q < 8; ++q)
    mcp += rdv[q] + __logf(a[q]);    // trow == 1 (one-hot targets)

  float ep = partE[tid];
  float cp = (tid < 8) ? partCol[tid] : 0.f;

  float total = bsum(-mcp - 0.5f * (cp + ep));
  if (tid == 0) out[0] = total;
}

extern "C" void kernel_launch(void* const* d_in, const int* in_sizes, int n_in,
                              void* d_out, int out_size, void* d_ws, size_t ws_size,
                              hipStream_t stream)
{
  const float* features = (const float*)d_in[0];  // [8192][512]
  const float* ml_text  = (const float*)d_in[1];  // [2048][512]
  const float* mc_text  = (const float*)d_in[2];  // [1000][512]
  const float* ml_tgt   = (const float*)d_in[3];  // [8192][2048]
  const float* mc_tgt   = (const float*)d_in[4];  // [8192][1000]
  const int*   dsidx    = (const int*)d_in[5];    // [8192]
  const float* ratios   = (const float*)d_in[6];  // [2048]
  float* out = (float*)d_out;

  char* ws = (char*)d_ws;
  size_t off = 0;
  auto alloc = [&](size_t bytes) -> void* {
    void* p = ws + off;
    off += (bytes + 255) & ~(size_t)255;
    return p;
  };
  u16*   Abf    = (u16*)alloc((size_t)8192 * 512 * 2);
  u16*   Bbf    = (u16*)alloc((size_t)3072 * 512 * 2);
  u16*   Sml    = (u16*)alloc((size_t)8192 * 2048 * 2);
  float* part1  = (float*)alloc((size_t)64 * 2048 * 4);
  float* cbuf   = (float*)alloc((size_t)2048 * 2 * 4);
  float* part2  = (float*)alloc((size_t)1024 * 2048 * 4);
  float* partT  = (float*)alloc((size_t)1024 * 2048 * 4);
  float* pA2    = (float*)alloc((size_t)64 * 2048 * 4);
  float* pAT    = (float*)alloc((size_t)64 * 2048 * 4);
  float* partE  = (float*)alloc((size_t)1024 * 4);
  float* partCol= (float*)alloc((size_t)8 * 4);
  float* pexp   = (float*)alloc((size_t)8 * 8192 * 4);
  float* Rbuf   = (float*)alloc((size_t)8192 * 4);
  float* rowdot = (float*)alloc((size_t)8192 * 4);

  k_cvt_all<<<(1441792 + 255) / 256, 256, 0, stream>>>(features, ml_text, mc_text, Abf, Bbf);

  const float scale = 1.0f / 0.07f;
  k_gemm_fused<<<1536, 512, 0, stream>>>(Abf, Bbf, Sml, part1, pexp, scale);

  k_misc<<<2088, 256, 0, stream>>>(part1, ratios, cbuf, mc_tgt, Abf, Bbf, rowdot, pexp, Rbuf, scale);
  k_ml_pass2<<<1024, 256, 0, stream>>>(Sml, ml_tgt, cbuf, part2, partT, partE);
  k_colredA<<<dim3(8, 64), 256, 0, stream>>>(part2, partT, pA2, pAT);
  k_colredB<<<8, 256, 0, stream>>>(pA2, pAT, ratios, partCol);
  k_finalize<<<1, 1024, 0, stream>>>(Rbuf, rowdot, dsidx, partE, partCol, out);
}